// Round 1
// baseline (429.980 us; speedup 1.0000x reference)
//
#include <hip/hip_runtime.h>

#define DIM 128
#define MOMENTUM 0.5f

// Grid-stride float4 copy: memory -> out. The m13-pattern copy measured
// ~6.3 TB/s on MI355X; this replaces hipMemcpyAsync, whose in-graph D2D
// path appears to run far below peak (theory: SDMA / conservative
// copyBuffer config accounts for most of the 418 us).
__global__ __launch_bounds__(256) void bank_copy_f4(const float4* __restrict__ src,
                                                    float4* __restrict__ dst,
                                                    long long n4) {
    long long i = (long long)blockIdx.x * blockDim.x + threadIdx.x;
    const long long stride = (long long)gridDim.x * blockDim.x;
    for (; i < n4; i += stride)
        dst[i] = src[i];
}

// One wave (64 lanes) per row. Each lane owns 2 consecutive floats (float2).
// Row source values are read from `out` (already holds the copy of `memory`
// because the copy kernel precedes this on the same stream).
__global__ void FeatureBank_update_rows(const float* __restrict__ x,
                                        const int* __restrict__ y,
                                        float* __restrict__ out,
                                        int batch) {
    const int lane = threadIdx.x & 63;
    const int wave = threadIdx.x >> 6;
    const int row = blockIdx.x * (blockDim.x >> 6) + wave;
    if (row >= batch) return;

    const long long dst = (long long)y[row] * DIM;

    const float2 xv = ((const float2*)(x + (long long)row * DIM))[lane];
    const float2 mv = ((const float2*)(out + dst))[lane];

    float2 w;
    w.x = MOMENTUM * mv.x + (1.0f - MOMENTUM) * xv.x;
    w.y = MOMENTUM * mv.y + (1.0f - MOMENTUM) * xv.y;

    float ss = w.x * w.x + w.y * w.y;
    // wave64 butterfly reduction
    #pragma unroll
    for (int off = 32; off > 0; off >>= 1)
        ss += __shfl_xor(ss, off, 64);

    const float inv = rsqrtf(ss);
    float2 o;
    o.x = w.x * inv;
    o.y = w.y * inv;
    ((float2*)(out + dst))[lane] = o;
}

extern "C" void kernel_launch(void* const* d_in, const int* in_sizes, int n_in,
                              void* d_out, int out_size, void* d_ws, size_t ws_size,
                              hipStream_t stream) {
    const float* x      = (const float*)d_in[0];
    const int*   y      = (const int*)d_in[1];
    const float* memory = (const float*)d_in[2];
    float*       out    = (float*)d_out;

    const int batch = in_sizes[1];                 // 4096
    const long long n4 = (long long)out_size / 4;  // 64e6 floats -> 16e6 float4

    // Bulk copy memory -> out with a shader copy at HBM rate.
    // grid: 2048 blocks x 256 threads = 512K threads, ~30 float4/thread.
    bank_copy_f4<<<2048, 256, 0, stream>>>((const float4*)memory, (float4*)out, n4);

    // Update the touched rows in place.
    const int waves_per_block = 4;                 // 256 threads
    const int block = 64 * waves_per_block;
    const int grid = (batch + waves_per_block - 1) / waves_per_block;
    FeatureBank_update_rows<<<grid, block, 0, stream>>>(x, y, out, batch);
}